// Round 3
// baseline (72.020 us; speedup 1.0000x reference)
//
#include <hip/hip_runtime.h>

#define BLOCK   256
#define SPL     8     // sources per lane (8 -> halves wave count & DS traffic)
#define TSPLIT  64    // target chunks (partial-min buffer depth)
#define CHT_MAX 256   // max targets per chunk the LDS stage supports

typedef float vfloat2 __attribute__((ext_vector_type(2)));
typedef float vfloat4 __attribute__((ext_vector_type(4)));

__device__ __forceinline__ vfloat2 vlo(vfloat4 v) { return __builtin_shufflevector(v, v, 0, 1); }
__device__ __forceinline__ vfloat2 vhi(vfloat4 v) { return __builtin_shufflevector(v, v, 2, 3); }

// ---- Kernel A (pass 1, FUSED prep+scan): each block stages its own target
// chunk AoS->LDS-SoA (x|y|z|w, w=|t|^2; pad w=1e30 sentinel), then scans it
// with EIGHT SOURCES PER LANE from uniform-address ds_read_b128 (LDS
// broadcast, conflict-free). DS insts/wave/target = 1 (fixed), so SPL=8
// halves device-wide DS traffic vs SPL=4 — attacks the LDS-return-BW bound
// (~12 cyc per wave b128, m134). 128 VALU insts per 8 DS reads.
// NO cross-lane reduction in the loop.
__global__ __launch_bounds__(BLOCK, 2) void nn_chunk_kernel(
    const float* __restrict__ src, const float* __restrict__ tgt,
    float* __restrict__ partial, float* __restrict__ out,
    int N, int M, int CHT, int SGB, int BN)
{
    const int tid = threadIdx.x;
    const int c   = blockIdx.x % TSPLIT;         // target chunk  (uniform)
    const int sgg = blockIdx.x / TSPLIT;
    const int b   = sgg / SGB;                   // batch         (uniform)
    const int sgl = sgg - b * SGB;
    const int si0 = sgl * (BLOCK * SPL) + tid;   // first source of this lane

    if (blockIdx.x == 0 && tid == 0) out[0] = 0.f;   // replaces prep's init

    // ---- stage this block's chunk into LDS as SoA (+ precomputed |t|^2) ----
    __shared__ __align__(16) float sxl[CHT_MAX];
    __shared__ __align__(16) float syl[CHT_MAX];
    __shared__ __align__(16) float szl[CHT_MAX];
    __shared__ __align__(16) float swl[CHT_MAX];
    if (tid < CHT) {
        const int m = c * CHT + tid;
        float x = 0.f, y = 0.f, z = 0.f, w = 1e30f;  // pad: never wins the min
        if (m < M) {
            const float* p = tgt + ((size_t)b * M + m) * 3;
            x = p[0]; y = p[1]; z = p[2];
            w = fmaf(x, x, fmaf(y, y, z * z));
        }
        sxl[tid] = x; syl[tid] = y; szl[tid] = z; swl[tid] = w;
    }

    // per-lane sources, pre-scaled by -2, splatted to pk pairs
    vfloat2 nsx[SPL], nsy[SPL], nsz[SPL];
    float mind[SPL];
#pragma unroll
    for (int s = 0; s < SPL; ++s) {
        const int si = si0 + s * BLOCK;
        float x = 0.f, y = 0.f, z = 0.f;
        if (si < N) {
            const float* p = src + ((size_t)b * N + si) * 3;
            x = p[0]; y = p[1]; z = p[2];
        }
        nsx[s] = {-2.f * x, -2.f * x};
        nsy[s] = {-2.f * y, -2.f * y};
        nsz[s] = {-2.f * z, -2.f * z};
        mind[s] = 1e30f;
    }

    __syncthreads();

    const vfloat4* __restrict__ TX = (const vfloat4*)sxl;
    const vfloat4* __restrict__ TY = (const vfloat4*)syl;
    const vfloat4* __restrict__ TZ = (const vfloat4*)szl;
    const vfloat4* __restrict__ TW = (const vfloat4*)swl;

#pragma unroll 2
    for (int k = 0; k < CHT / 8; ++k) {
        // 8 uniform ds_read_b128 in flight -> 8 targets (shared by 8 sources)
        vfloat4 xa = TX[2 * k], xb = TX[2 * k + 1];
        vfloat4 ya = TY[2 * k], yb = TY[2 * k + 1];
        vfloat4 za = TZ[2 * k], zb = TZ[2 * k + 1];
        vfloat4 wa = TW[2 * k], wb = TW[2 * k + 1];

#pragma unroll
        for (int s = 0; s < SPL; ++s) {
            vfloat2 d;
            d = __builtin_elementwise_fma(vlo(xa), nsx[s], vlo(wa));
            d = __builtin_elementwise_fma(vlo(ya), nsy[s], d);
            d = __builtin_elementwise_fma(vlo(za), nsz[s], d);
            mind[s] = fminf(mind[s], fminf(d.x, d.y));   // v_min3_f32

            d = __builtin_elementwise_fma(vhi(xa), nsx[s], vhi(wa));
            d = __builtin_elementwise_fma(vhi(ya), nsy[s], d);
            d = __builtin_elementwise_fma(vhi(za), nsz[s], d);
            mind[s] = fminf(mind[s], fminf(d.x, d.y));

            d = __builtin_elementwise_fma(vlo(xb), nsx[s], vlo(wb));
            d = __builtin_elementwise_fma(vlo(yb), nsy[s], d);
            d = __builtin_elementwise_fma(vlo(zb), nsz[s], d);
            mind[s] = fminf(mind[s], fminf(d.x, d.y));

            d = __builtin_elementwise_fma(vhi(xb), nsx[s], vhi(wb));
            d = __builtin_elementwise_fma(vhi(yb), nsy[s], d);
            d = __builtin_elementwise_fma(vhi(zb), nsz[s], d);
            mind[s] = fminf(mind[s], fminf(d.x, d.y));
        }
    }

#pragma unroll
    for (int s = 0; s < SPL; ++s) {
        const int si = si0 + s * BLOCK;
        if (si < N) {
            partial[(size_t)c * BN + (size_t)b * N + si] = mind[s];  // coalesced
        }
    }
}

// ---- Kernel B (pass 2): per source min over chunks, +|s|^2, sum, atomic ----
__global__ __launch_bounds__(BLOCK) void reduce_kernel(
    const float* __restrict__ src, const float* __restrict__ partial,
    float* __restrict__ out, int BN, float scale)
{
    const int i = blockIdx.x * BLOCK + threadIdx.x;
    float v = 0.f;
    if (i < BN) {
        float m0 = 1e30f, m1 = 1e30f, m2 = 1e30f, m3 = 1e30f;
#pragma unroll
        for (int c = 0; c < TSPLIT; c += 4) {
            m0 = fminf(m0, partial[(size_t)(c + 0) * BN + i]);
            m1 = fminf(m1, partial[(size_t)(c + 1) * BN + i]);
            m2 = fminf(m2, partial[(size_t)(c + 2) * BN + i]);
            m3 = fminf(m3, partial[(size_t)(c + 3) * BN + i]);
        }
        float x = src[(size_t)i * 3 + 0];
        float y = src[(size_t)i * 3 + 1];
        float z = src[(size_t)i * 3 + 2];
        v = fmaf(x, x, fmaf(y, y, z * z))
          + fminf(fminf(m0, m1), fminf(m2, m3));     // = min ||s-t||^2
    }

#pragma unroll
    for (int off = 32; off > 0; off >>= 1) v += __shfl_xor(v, off, 64);

    __shared__ float wsum[BLOCK / 64];
    const int lane = threadIdx.x & 63;
    const int w    = threadIdx.x >> 6;
    if (lane == 0) wsum[w] = v;
    __syncthreads();
    if (threadIdx.x == 0) {
        float s = 0.f;
#pragma unroll
        for (int k = 0; k < BLOCK / 64; ++k) s += wsum[k];
        atomicAdd(out, s * scale);
    }
}

extern "C" void kernel_launch(void* const* d_in, const int* in_sizes, int n_in,
                              void* d_out, int out_size, void* d_ws, size_t ws_size,
                              hipStream_t stream) {
    const float* src = (const float*)d_in[0];  // [B, N, 3] fp32
    const float* tgt = (const float*)d_in[1];  // [B, M, 3] fp32
    float* out = (float*)d_out;                // scalar fp32

    const int B = 2;
    const int N = in_sizes[0] / (B * 3);
    const int M = in_sizes[1] / (B * 3);
    const int BN = B * N;

    // targets per chunk, padded to a multiple of 8 (8192 -> CHT=128)
    const int CHT = ((M + TSPLIT * 8 - 1) / (TSPLIT * 8)) * 8;

    float* partial = (float*)d_ws;                    // TSPLIT*BN floats (4 MB)

    const int SPB = BLOCK * SPL;                      // sources per block
    const int SGB = (N + SPB - 1) / SPB;              // source groups / batch
    const int grid1 = B * SGB * TSPLIT;               // 512 blocks
    nn_chunk_kernel<<<grid1, BLOCK, 0, stream>>>(src, tgt, partial, out,
                                                 N, M, CHT, SGB, BN);

    reduce_kernel<<<(BN + BLOCK - 1) / BLOCK, BLOCK, 0, stream>>>(
        src, partial, out, BN, 1.0f / (3.0f * (float)N * (float)B));
}

// Round 5
// 70.162 us; speedup vs baseline: 1.0265x; 1.0265x over previous
//
#include <hip/hip_runtime.h>

#define BLOCK   256
#define SPL     4     // sources per lane (best measured: R2 = 70.3 us)
#define TSPLIT  64    // target chunks (partial-min buffer depth)
#define CHT_MAX 256   // max targets per chunk the LDS stage supports

typedef float vfloat2 __attribute__((ext_vector_type(2)));
typedef float vfloat4 __attribute__((ext_vector_type(4)));

__device__ __forceinline__ vfloat2 vlo(vfloat4 v) { return __builtin_shufflevector(v, v, 0, 1); }
__device__ __forceinline__ vfloat2 vhi(vfloat4 v) { return __builtin_shufflevector(v, v, 2, 3); }

// ---- Kernel A (pass 1, FUSED prep+scan): each block stages its own target
// chunk AoS->LDS-SoA (x|y|z|w, w=|t|^2; pad w=1e30 sentinel), then scans it
// with FOUR SOURCES PER LANE from uniform-address ds_read_b128 (LDS broadcast,
// conflict-free). 3 v_pk_fma + 1 v_min3 per 2 targets per source.
// NO cross-lane reduction in the loop.
// NOTE (session findings): inner loop is balanced at SPL=4 — SPL=8 (half DS
// traffic) regressed +1.7us (R3), SPL=1->4 (quarter VMEM) was null (R1).
// Cooperative-launch single-node fusion FAILS under graph capture (R4,
// absmax 7.9e-3 stale partials) — do not retry grid.sync here.
__global__ __launch_bounds__(BLOCK, 4) void nn_chunk_kernel(
    const float* __restrict__ src, const float* __restrict__ tgt,
    float* __restrict__ partial, float* __restrict__ out,
    int N, int M, int CHT, int SGB, int BN)
{
    const int tid = threadIdx.x;
    const int c   = blockIdx.x % TSPLIT;         // target chunk  (uniform)
    const int sgg = blockIdx.x / TSPLIT;
    const int b   = sgg / SGB;                   // batch         (uniform)
    const int sgl = sgg - b * SGB;
    const int si0 = sgl * (BLOCK * SPL) + tid;   // first source of this lane

    if (blockIdx.x == 0 && tid == 0) out[0] = 0.f;   // safe: pass 2 is a later node

    // ---- stage this block's chunk into LDS as SoA (+ precomputed |t|^2) ----
    __shared__ __align__(16) float sxl[CHT_MAX];
    __shared__ __align__(16) float syl[CHT_MAX];
    __shared__ __align__(16) float szl[CHT_MAX];
    __shared__ __align__(16) float swl[CHT_MAX];
    if (tid < CHT) {
        const int m = c * CHT + tid;
        float x = 0.f, y = 0.f, z = 0.f, w = 1e30f;  // pad: never wins the min
        if (m < M) {
            const float* p = tgt + ((size_t)b * M + m) * 3;
            x = p[0]; y = p[1]; z = p[2];
            w = fmaf(x, x, fmaf(y, y, z * z));
        }
        sxl[tid] = x; syl[tid] = y; szl[tid] = z; swl[tid] = w;
    }

    // per-lane sources, pre-scaled by -2, splatted to pk pairs
    vfloat2 nsx[SPL], nsy[SPL], nsz[SPL];
    float mind[SPL];
#pragma unroll
    for (int s = 0; s < SPL; ++s) {
        const int si = si0 + s * BLOCK;
        float x = 0.f, y = 0.f, z = 0.f;
        if (si < N) {
            const float* p = src + ((size_t)b * N + si) * 3;
            x = p[0]; y = p[1]; z = p[2];
        }
        nsx[s] = {-2.f * x, -2.f * x};
        nsy[s] = {-2.f * y, -2.f * y};
        nsz[s] = {-2.f * z, -2.f * z};
        mind[s] = 1e30f;
    }

    __syncthreads();

    const vfloat4* __restrict__ TX = (const vfloat4*)sxl;
    const vfloat4* __restrict__ TY = (const vfloat4*)syl;
    const vfloat4* __restrict__ TZ = (const vfloat4*)szl;
    const vfloat4* __restrict__ TW = (const vfloat4*)swl;

#pragma unroll 2
    for (int k = 0; k < CHT / 8; ++k) {
        // 8 uniform ds_read_b128 in flight -> 8 targets (shared by 4 sources)
        vfloat4 xa = TX[2 * k], xb = TX[2 * k + 1];
        vfloat4 ya = TY[2 * k], yb = TY[2 * k + 1];
        vfloat4 za = TZ[2 * k], zb = TZ[2 * k + 1];
        vfloat4 wa = TW[2 * k], wb = TW[2 * k + 1];

#pragma unroll
        for (int s = 0; s < SPL; ++s) {
            vfloat2 d;
            d = __builtin_elementwise_fma(vlo(xa), nsx[s], vlo(wa));
            d = __builtin_elementwise_fma(vlo(ya), nsy[s], d);
            d = __builtin_elementwise_fma(vlo(za), nsz[s], d);
            mind[s] = fminf(mind[s], fminf(d.x, d.y));   // v_min3_f32

            d = __builtin_elementwise_fma(vhi(xa), nsx[s], vhi(wa));
            d = __builtin_elementwise_fma(vhi(ya), nsy[s], d);
            d = __builtin_elementwise_fma(vhi(za), nsz[s], d);
            mind[s] = fminf(mind[s], fminf(d.x, d.y));

            d = __builtin_elementwise_fma(vlo(xb), nsx[s], vlo(wb));
            d = __builtin_elementwise_fma(vlo(yb), nsy[s], d);
            d = __builtin_elementwise_fma(vlo(zb), nsz[s], d);
            mind[s] = fminf(mind[s], fminf(d.x, d.y));

            d = __builtin_elementwise_fma(vhi(xb), nsx[s], vhi(wb));
            d = __builtin_elementwise_fma(vhi(yb), nsy[s], d);
            d = __builtin_elementwise_fma(vhi(zb), nsz[s], d);
            mind[s] = fminf(mind[s], fminf(d.x, d.y));
        }
    }

#pragma unroll
    for (int s = 0; s < SPL; ++s) {
        const int si = si0 + s * BLOCK;
        if (si < N) {
            partial[(size_t)c * BN + (size_t)b * N + si] = mind[s];  // coalesced
        }
    }
}

// ---- Kernel B (pass 2): per source min over chunks, +|s|^2, sum, atomic ----
__global__ __launch_bounds__(BLOCK) void reduce_kernel(
    const float* __restrict__ src, const float* __restrict__ partial,
    float* __restrict__ out, int BN, float scale)
{
    const int i = blockIdx.x * BLOCK + threadIdx.x;
    float v = 0.f;
    if (i < BN) {
        float m0 = 1e30f, m1 = 1e30f, m2 = 1e30f, m3 = 1e30f;
#pragma unroll
        for (int c = 0; c < TSPLIT; c += 4) {
            m0 = fminf(m0, partial[(size_t)(c + 0) * BN + i]);
            m1 = fminf(m1, partial[(size_t)(c + 1) * BN + i]);
            m2 = fminf(m2, partial[(size_t)(c + 2) * BN + i]);
            m3 = fminf(m3, partial[(size_t)(c + 3) * BN + i]);
        }
        float x = src[(size_t)i * 3 + 0];
        float y = src[(size_t)i * 3 + 1];
        float z = src[(size_t)i * 3 + 2];
        v = fmaf(x, x, fmaf(y, y, z * z))
          + fminf(fminf(m0, m1), fminf(m2, m3));     // = min ||s-t||^2
    }

#pragma unroll
    for (int off = 32; off > 0; off >>= 1) v += __shfl_xor(v, off, 64);

    __shared__ float wsum[BLOCK / 64];
    const int lane = threadIdx.x & 63;
    const int w    = threadIdx.x >> 6;
    if (lane == 0) wsum[w] = v;
    __syncthreads();
    if (threadIdx.x == 0) {
        float s = 0.f;
#pragma unroll
        for (int k = 0; k < BLOCK / 64; ++k) s += wsum[k];
        atomicAdd(out, s * scale);
    }
}

extern "C" void kernel_launch(void* const* d_in, const int* in_sizes, int n_in,
                              void* d_out, int out_size, void* d_ws, size_t ws_size,
                              hipStream_t stream) {
    const float* src = (const float*)d_in[0];  // [B, N, 3] fp32
    const float* tgt = (const float*)d_in[1];  // [B, M, 3] fp32
    float* out = (float*)d_out;                // scalar fp32

    const int B = 2;
    const int N = in_sizes[0] / (B * 3);
    const int M = in_sizes[1] / (B * 3);
    const int BN = B * N;

    // targets per chunk, padded to a multiple of 8 (8192 -> CHT=128)
    const int CHT = ((M + TSPLIT * 8 - 1) / (TSPLIT * 8)) * 8;

    float* partial = (float*)d_ws;                    // TSPLIT*BN floats (4 MB)

    const int SPB = BLOCK * SPL;                      // sources per block
    const int SGB = (N + SPB - 1) / SPB;              // source groups / batch
    const int grid1 = B * SGB * TSPLIT;               // 1024 blocks
    nn_chunk_kernel<<<grid1, BLOCK, 0, stream>>>(src, tgt, partial, out,
                                                 N, M, CHT, SGB, BN);

    reduce_kernel<<<(BN + BLOCK - 1) / BLOCK, BLOCK, 0, stream>>>(
        src, partial, out, BN, 1.0f / (3.0f * (float)N * (float)B));
}